// Round 1
// baseline (790.007 us; speedup 1.0000x reference)
//
#include <hip/hip_runtime.h>
#include <hip/hip_bf16.h>

// PositionEmbeddingEncoder: 1M points, 8 grid levels (g = 2^d), gather 8-float
// rows from per-level tables, concat -> [N, 64] f32.
//
// Layout: 8 threads per point, lane handles one depth. Stores are two float4s
// at out[point*64 + depth*8] -> consecutive lanes write contiguous 32B chunks,
// fully coalesced. Gathers from w8 (536 MB) are the only uncacheable traffic.

__global__ __launch_bounds__(256) void pe_encode_kernel(
    const float* __restrict__ x,
    const float* __restrict__ w1, const float* __restrict__ w2,
    const float* __restrict__ w3, const float* __restrict__ w4,
    const float* __restrict__ w5, const float* __restrict__ w6,
    const float* __restrict__ w7, const float* __restrict__ w8,
    float* __restrict__ out, int n)
{
    __shared__ const float* tabs[8];
    if (threadIdx.x == 0) {
        tabs[0] = w1; tabs[1] = w2; tabs[2] = w3; tabs[3] = w4;
        tabs[4] = w5; tabs[5] = w6; tabs[6] = w7; tabs[7] = w8;
    }
    __syncthreads();

    const int tid   = blockIdx.x * blockDim.x + threadIdx.x;
    const int point = tid >> 3;      // 8 lanes per point
    const int d     = tid & 7;       // depth-1 in [0,8)
    if (point >= n) return;

    // Load the point's coords (8 lanes of a group read the same 12B; L1 broadcast).
    const float px = x[point * 3 + 0];
    const float py = x[point * 3 + 1];
    const float pz = x[point * 3 + 2];

    // scaled = (x + 128) / 256  — /256 is an exact power-of-two scale, so the
    // reciprocal multiply is bit-identical to the reference's division.
    const float sx = (px + 128.0f) * (1.0f / 256.0f);
    const float sy = (py + 128.0f) * (1.0f / 256.0f);
    const float sz = (pz + 128.0f) * (1.0f / 256.0f);

    const int   g  = 2 << d;         // 2^(d+1)
    const float gf = (float)g;
    const float gm1 = gf - 1.0f;

    // clip(floor(s*g), 0, g-1) — same op order as the reference (no fma).
    const float cxf = fminf(fmaxf(floorf(sx * gf), 0.0f), gm1);
    const float cyf = fminf(fmaxf(floorf(sy * gf), 0.0f), gm1);
    const float czf = fminf(fmaxf(floorf(sz * gf), 0.0f), gm1);
    const int cx = (int)cxf, cy = (int)cyf, cz = (int)czf;

    const long long flat = (long long)cx + (long long)cy * g + (long long)cz * g * g;

    // Gather one 32B row (aligned: flat*32 bytes) as two float4s.
    const float4* row = (const float4*)(tabs[d] + flat * 8);
    const float4 r0 = row[0];
    const float4 r1 = row[1];

    // Store: float4 index = tid*2 — contiguous across the wave.
    float4* outv = (float4*)out;
    outv[(size_t)tid * 2 + 0] = r0;
    outv[(size_t)tid * 2 + 1] = r1;
}

extern "C" void kernel_launch(void* const* d_in, const int* in_sizes, int n_in,
                              void* d_out, int out_size, void* d_ws, size_t ws_size,
                              hipStream_t stream) {
    const float* x  = (const float*)d_in[0];
    const float* w1 = (const float*)d_in[1];
    const float* w2 = (const float*)d_in[2];
    const float* w3 = (const float*)d_in[3];
    const float* w4 = (const float*)d_in[4];
    const float* w5 = (const float*)d_in[5];
    const float* w6 = (const float*)d_in[6];
    const float* w7 = (const float*)d_in[7];
    const float* w8 = (const float*)d_in[8];
    float* out = (float*)d_out;

    const int n = in_sizes[0] / 3;           // 1,000,000 points
    const int threads = n * 8;               // 8 lanes per point
    const int block = 256;
    const int grid = (threads + block - 1) / block;

    pe_encode_kernel<<<grid, block, 0, stream>>>(x, w1, w2, w3, w4, w5, w6, w7, w8,
                                                 out, n);
}